// Round 10
// baseline (175.177 us; speedup 1.0000x reference)
//
#include <hip/hip_runtime.h>

#define CDIM 64
#define TDIM 24
#define NDIM 512
#define NBT  192   // B*T = 8*24

typedef float    float4v __attribute__((ext_vector_type(4)));
typedef _Float16 half8v  __attribute__((ext_vector_type(8)));
typedef _Float16 half4v  __attribute__((ext_vector_type(4)));
typedef _Float16 half2v  __attribute__((ext_vector_type(2)));

// ---------------------------------------------------------------------------
// Workspace layout (bytes):
//   VT_g   : _Float16 [NBT][64][512]   0          (12582912 B)
//   s_src  : float    [NBT][2][512]    12582912   (786432 B)   (exp2 domain)
//   s_dst  : float    [NBT][2][512]    13369344   (786432 B)   (exp2 domain)
//   maskb  : u8       [512][512]       14155776   (262144 B)   {0x00,0xFF}
// XCD note: both kernels use 1D grids with bt = bx % NBT, so all blocks
// sharing a bt land on XCD bt%8 (round-robin dispatch heuristic): VT[bt] is
// produced and consumed in the same XCD's L2.
// ---------------------------------------------------------------------------

__device__ __forceinline__ float exp2_fast(float x) {
#if __has_builtin(__builtin_amdgcn_exp2f)
  return __builtin_amdgcn_exp2f(x);
#else
  return __expf(x * 0.69314718f);
#endif
}

__device__ __forceinline__ half2v pk2(float a, float b) {
  return __builtin_bit_cast(half2v, __builtin_amdgcn_cvt_pkrtz(a, b));
}

// ======== kernel 1: V = X @ Wv^T (f16 MFMA) + score cols + mask pack ========
// (unchanged from R9)
struct SmemK1 {
  union {
    _Float16 xt[128][72];    // X tile [node][c], 144 B rows (16B aligned, b128-readable)
    _Float16 vtb[64][136];   // V^T bounce [c][node]
  } big;                     // 18432 B
  _Float16 wv[64][72];       // Wv [d][k]             9216 B
  _Float16 wext[16][72];     // rows 0..3 = log2e * (a_h^T W_h), rest 0   2304 B
};                            // 29952 B -> 4 blocks/CU

__launch_bounds__(256, 4)
__global__ void k1_v(const float* __restrict__ x,  const float* __restrict__ Wv,
                     const float* __restrict__ Wq, const float* __restrict__ Wk,
                     const float* __restrict__ a_src, const float* __restrict__ a_dst,
                     const int* __restrict__ gso,
                     _Float16* __restrict__ VT_g,
                     float* __restrict__ s_src_g, float* __restrict__ s_dst_g,
                     unsigned char* __restrict__ maskb) {
  const int t  = threadIdx.x;
  const int bx = blockIdx.x;

  if (bx >= 768) {   // ---- mask-pack blocks: 16 ints -> 16 mask bytes each ----
    int g = (bx - 768) * 256 + t;            // 0..16383
    const int4* gp = (const int4*)gso + (size_t)g * 4;
    unsigned w[4];
#pragma unroll
    for (int k = 0; k < 4; ++k) {
      int4 v = gp[k];
      w[k] = (v.x ? 0x000000FFu : 0u) | (v.y ? 0x0000FF00u : 0u) |
             (v.z ? 0x00FF0000u : 0u) | (v.w ? 0xFF000000u : 0u);
    }
    uint4 o; o.x = w[0]; o.y = w[1]; o.z = w[2]; o.w = w[3];
    ((uint4*)maskb)[g] = o;
    return;
  }

  __shared__ SmemK1 sm;
  const int bt = bx % NBT;       // XCD = bt % 8
  const int qn = bx / NBT;
  const int b  = bt / TDIM, tt = bt % TDIM;
  const int n0 = qn * 128;

  // stage Wv -> f16 LDS (float4 + pkrtz, half4 stores)
#pragma unroll
  for (int it = 0; it < 4; ++it) {
    int idx = it * 256 + t;           // 1024 float4 chunks
    int d = idx >> 4, k4 = (idx & 15) * 4;
    float4 v = ((const float4*)Wv)[idx];
    half2v p0 = pk2(v.x, v.y), p1 = pk2(v.z, v.w);
    half4v h4; h4[0] = p0[0]; h4[1] = p0[1]; h4[2] = p1[0]; h4[3] = p1[1];
    *(half4v*)&sm.wv[d][k4] = h4;
  }
  // wext: zero rows 4..15; rows 0..3 = log2e * (a_h^T W_h)  (exp2 domain)
  for (int z = t; z < 12 * 72; z += 256) ((_Float16*)sm.wext[4])[z] = (_Float16)0.f;
  {
    int r = t >> 6, c = t & 63;
    const float* av = (r & 2) ? a_dst : a_src;
    const float* W  = (r & 2) ? Wk : Wq;
    int off = (r & 1) * 32;
    float s = 0.f;
#pragma unroll
    for (int d = 0; d < 32; ++d)
      s += av[off + d] * W[(off + d) * 64 + c];
    sm.wext[r][c] = (_Float16)(s * 1.44269504f);
  }
  // stage X tile (channel pairs -> half2)
  for (int it = 0; it < 16; ++it) {
    int idx = it * 256 + t;
    int cp = idx >> 7, n = idx & 127;
    int c0 = cp * 2;
    const float* base = x + ((size_t)(b * CDIM + c0) * TDIM + tt) * NDIM + n0 + n;
    *(half2v*)&sm.big.xt[n][c0] = pk2(base[0], base[(size_t)TDIM * NDIM]);
  }
  __syncthreads();

  const int lane = t & 63, w = t >> 6;
  const int m = lane & 15, quad = lane >> 4;
  const int mbase = w * 32;   // 32 nodes per wave

  float4v acc[2][5];
#pragma unroll
  for (int mt = 0; mt < 2; ++mt)
#pragma unroll
    for (int nt = 0; nt < 5; ++nt)
#pragma unroll
      for (int r = 0; r < 4; ++r) acc[mt][nt][r] = 0.f;

#pragma unroll
  for (int ks = 0; ks < 2; ++ks) {
    half8v af[2], bf[5];
#pragma unroll
    for (int mt = 0; mt < 2; ++mt)
      af[mt] = *(const half8v*)&sm.big.xt[mbase + mt * 16 + m][ks * 32 + quad * 8];
#pragma unroll
    for (int nt = 0; nt < 4; ++nt)
      bf[nt] = *(const half8v*)&sm.wv[nt * 16 + m][ks * 32 + quad * 8];
    bf[4] = *(const half8v*)&sm.wext[m][ks * 32 + quad * 8];
#pragma unroll
    for (int mt = 0; mt < 2; ++mt)
#pragma unroll
      for (int nt = 0; nt < 5; ++nt)
        acc[mt][nt] = __builtin_amdgcn_mfma_f32_16x16x32_f16(af[mt], bf[nt], acc[mt][nt], 0, 0, 0);
  }

  // scatter score columns (col 0/1 = ssrc h0/h1, col 2/3 = sdst h0/h1)
  if (m < 4) {
    float* basep = (m < 2 ? s_src_g : s_dst_g) + (size_t)(bt * 2 + (m & 1)) * NDIM;
#pragma unroll
    for (int mt = 0; mt < 2; ++mt)
#pragma unroll
      for (int r = 0; r < 4; ++r)
        basep[n0 + mbase + mt * 16 + quad * 4 + r] = acc[mt][4][r];
  }
  __syncthreads();   // xt fully consumed before overlay

  // V^T bounce into LDS (pack node pairs)
#pragma unroll
  for (int mt = 0; mt < 2; ++mt)
#pragma unroll
    for (int nt = 0; nt < 4; ++nt)
#pragma unroll
      for (int r = 0; r < 4; r += 2) {
        int nl = mbase + mt * 16 + quad * 4 + r;
        int c  = nt * 16 + m;
        *(half2v*)&sm.big.vtb[c][nl] = pk2(acc[mt][nt][r], acc[mt][nt][r + 1]);
      }
  __syncthreads();

  // coalesced V^T -> global (64 rows x 64 dwords)
  const unsigned* vdw = (const unsigned*)sm.big.vtb;   // row stride 68 dwords
  unsigned* outdw = (unsigned*)VT_g;
  for (int it = 0; it < 16; ++it) {
    int idx = it * 256 + t;
    int c = idx >> 6, jd = idx & 63;
    outdw[(size_t)(bt * 64 + c) * 256 + qn * 64 + jd] = vdw[c * 68 + jd];
  }
}

// ======== kernel 2: masked softmax(P) @ V + LayerNorm + transpose ===========
// 1D grid, 1536 blocks: bt = bx % NBT (XCD-aligned with k1's VT writer).
// Software-pipelined js-loop: js+1's V-staging + mask loads issue into
// registers BEFORE js's compute; double-buffered vt; ONE barrier per js whose
// drain covers only LDS stores (global loads issued a full iteration earlier).
struct SmemK2 {
  union {
    _Float16 vt[2][64][128];     // 32768 B double-buffered swizzled V^T quarter
    float otile[64][66];         // 16896 B epilogue overlay
  } u;                           // 32768 B
  union {
    struct { _Float16 F[2][512]; _Float16 P[2][512]; } f;                          // 4096 B
    struct { float rsum[4][64]; float rsq[4][64]; float mu[64]; float rs[64]; } l; // 2560 B
  } v;
};                                // 36864 B -> 4 blocks/CU

__launch_bounds__(256, 4)
__global__ void k2_attn(const _Float16* __restrict__ VT_g,
                        const float* __restrict__ s_src_g, const float* __restrict__ s_dst_g,
                        const unsigned char* __restrict__ maskb,
                        const float* __restrict__ gamma, const float* __restrict__ beta,
                        float* __restrict__ out) {
  __shared__ SmemK2 sm;
  const int t     = threadIdx.x;
  const int bx    = blockIdx.x;
  const int bt    = bx % NBT;    // XCD = bt % 8
  const int itile = bx / NBT;
  const int i0    = itile * 64;
  const int b     = bt / TDIM, tt = bt % TDIM;
  const int lane  = t & 63, w = t >> 6;
  const int h = w >> 1, ihalf = w & 1;
  const int m = lane & 15, quad = lane >> 4;

  const unsigned char* mrow0 = maskb + (size_t)(i0 + ihalf * 32 + m) * NDIM;
  const unsigned char* mrow1 = mrow0 + 16 * NDIM;
  const uint4* vsrc = (const uint4*)VT_g + (size_t)bt * 64 * 64;  // 64 rows x 64 uint4
  const int r0 = h * 32 + m;
  const int rsw = (r0 & 7) * 8;
  const int sc = t >> 4, sch = t & 15;   // staging row / chunk for this thread

  // ---- prologue: issue js=0 V-staging + mask loads immediately ----
  uint4 pre[4];
#pragma unroll
  for (int it = 0; it < 4; ++it)
    pre[it] = vsrc[(sc + it * 16) * 64 + sch];
  uint2 mpre0[4], mpre1[4];
#pragma unroll
  for (int k = 0; k < 4; ++k) {
    int jo = k * 32 + quad * 8;
    mpre0[k] = *(const uint2*)(mrow0 + jo);
    mpre1[k] = *(const uint2*)(mrow1 + jo);
  }

  // ---- F/P staging + row factors (overlaps prologue load latency) ----
  for (int it = 0; it < 4; ++it) {
    int idx = it * 256 + t;
    float d = s_dst_g[(size_t)bt * 2 * NDIM + idx];
    ((_Float16*)sm.v.f.F)[idx] = (_Float16)exp2_fast(d);
    ((_Float16*)sm.v.f.P)[idx] = (_Float16)exp2_fast(0.2f * d);
  }
  half8v E8[2], Q8[2];
#pragma unroll
  for (int mt = 0; mt < 2; ++mt) {
    float sv = s_src_g[(size_t)(bt * 2 + h) * NDIM + i0 + ihalf * 32 + mt * 16 + m];
    _Float16 ev = (_Float16)exp2_fast(sv - 6.f);
    _Float16 qv = (_Float16)exp2_fast(0.2f * sv - 6.f);
#pragma unroll
    for (int jj = 0; jj < 8; ++jj) { E8[mt][jj] = ev; Q8[mt][jj] = qv; }
  }

  float4v acc[2][2], accs[2];
#pragma unroll
  for (int mt = 0; mt < 2; ++mt) {
#pragma unroll
    for (int r = 0; r < 4; ++r) { acc[mt][0][r] = 0.f; acc[mt][1][r] = 0.f; accs[mt][r] = 0.f; }
  }
  const half8v bones = {(_Float16)1.f, (_Float16)1.f, (_Float16)1.f, (_Float16)1.f,
                        (_Float16)1.f, (_Float16)1.f, (_Float16)1.f, (_Float16)1.f};

  for (int js = 0; js < 4; ++js) {
    // issue NEXT js loads first (stay in flight across this js's compute)
    uint4 nxt[4]; uint2 mn0[4], mn1[4];
    if (js < 3) {
#pragma unroll
      for (int it = 0; it < 4; ++it)
        nxt[it] = vsrc[(sc + it * 16) * 64 + (js + 1) * 16 + sch];
#pragma unroll
      for (int k = 0; k < 4; ++k) {
        int jo = (js + 1) * 128 + k * 32 + quad * 8;
        mn0[k] = *(const uint2*)(mrow0 + jo);
        mn1[k] = *(const uint2*)(mrow1 + jo);
      }
    }
    // store current prefetch to LDS buffer js&1 (waits only pre's old loads)
    {
      _Float16* vbuf = &sm.u.vt[js & 1][0][0];
#pragma unroll
      for (int it = 0; it < 4; ++it) {
        int c = sc + it * 16;
        *(uint4*)&vbuf[c * 128 + ((sch * 8) ^ ((c & 7) * 8))] = pre[it];
      }
    }
    __syncthreads();   // lgkm drain only; also covers F/P stage on js=0

    const _Float16* vb = &sm.u.vt[js & 1][0][0];
#pragma unroll
    for (int ksl = 0; ksl < 4; ++ksl) {
      int jq = ksl * 32 + quad * 8;   // j within quarter
      int jo = js * 128 + jq;         // absolute j
      half8v F8 = *(const half8v*)&sm.v.f.F[h][jo];
      half8v P8 = *(const half8v*)&sm.v.f.P[h][jo];
      half8v b0 = *(const half8v*)&vb[r0 * 128 + (jq ^ rsw)];
      half8v b1 = *(const half8v*)&vb[(r0 + 16) * 128 + (jq ^ rsw)];
#pragma unroll
      for (int mt = 0; mt < 2; ++mt) {
        uint2 mv = mt ? mpre1[ksl] : mpre0[ksl];
        half8v e8 = __builtin_elementwise_max(E8[mt] * F8, Q8[mt] * P8);  // pk_mul/pk_max
        uint4 eu = __builtin_bit_cast(uint4, e8);
        eu.x &= __builtin_amdgcn_perm(0u, mv.x, 0x01010000u);
        eu.y &= __builtin_amdgcn_perm(0u, mv.x, 0x03030202u);
        eu.z &= __builtin_amdgcn_perm(0u, mv.y, 0x01010000u);
        eu.w &= __builtin_amdgcn_perm(0u, mv.y, 0x03030202u);
        half8v af = __builtin_bit_cast(half8v, eu);
        acc[mt][0] = __builtin_amdgcn_mfma_f32_16x16x32_f16(af, b0,    acc[mt][0], 0, 0, 0);
        acc[mt][1] = __builtin_amdgcn_mfma_f32_16x16x32_f16(af, b1,    acc[mt][1], 0, 0, 0);
        accs[mt]   = __builtin_amdgcn_mfma_f32_16x16x32_f16(af, bones, accs[mt],   0, 0, 0);
      }
    }
#pragma unroll
    for (int it = 0; it < 4; ++it) pre[it] = nxt[it];
#pragma unroll
    for (int k = 0; k < 4; ++k) { mpre0[k] = mn0[k]; mpre1[k] = mn1[k]; }
  }

  __syncthreads();   // vt dead -> otile overlay
  // normalize by row sums (same C-layout row as acc -> no shuffle needed)
#pragma unroll
  for (int mt = 0; mt < 2; ++mt)
#pragma unroll
    for (int r = 0; r < 4; ++r) {
      float sc2 = __builtin_amdgcn_rcpf(accs[mt][r]);
      int i_loc = ihalf * 32 + mt * 16 + quad * 4 + r;
#pragma unroll
      for (int nt = 0; nt < 2; ++nt)
        sm.u.otile[i_loc][h * 32 + nt * 16 + m] = acc[mt][nt][r] * sc2;
    }
  __syncthreads();

  // LayerNorm over C=64 per row
  {
    int i = t & 63, cg = t >> 6;
    float s1 = 0.f, s2 = 0.f;
#pragma unroll
    for (int cc = 0; cc < 16; ++cc) {
      float v = sm.u.otile[i][cg * 16 + cc];
      s1 += v; s2 += v * v;
    }
    sm.v.l.rsum[cg][i] = s1;
    sm.v.l.rsq[cg][i]  = s2;
  }
  __syncthreads();
  if (t < 64) {
    int i = t;
    float s1 = 0.f, s2 = 0.f;
#pragma unroll
    for (int cg = 0; cg < 4; ++cg) { s1 += sm.v.l.rsum[cg][i]; s2 += sm.v.l.rsq[cg][i]; }
    float mu  = s1 * (1.f / 64.f);
    float var = s2 * (1.f / 64.f) - mu * mu;
    sm.v.l.mu[i] = mu;
    sm.v.l.rs[i] = rsqrtf(var + 1e-5f);
  }
  __syncthreads();
  {
    int i = t & 63, cg = t >> 6;
    float mu = sm.v.l.mu[i], rs = sm.v.l.rs[i];
    int n = i0 + i;
#pragma unroll
    for (int cc = 0; cc < 16; ++cc) {
      int c = cg * 16 + cc;
      float v = (sm.u.otile[i][c] - mu) * rs * gamma[c] + beta[c];
      out[((size_t)(b * CDIM + c) * TDIM + tt) * NDIM + n] = v;
    }
  }
}

// ---------------------------------------------------------------------------
extern "C" void kernel_launch(void* const* d_in, const int* in_sizes, int n_in,
                              void* d_out, int out_size, void* d_ws, size_t ws_size,
                              hipStream_t stream) {
  const float* x     = (const float*)d_in[0];
  const int*   gso   = (const int*)d_in[1];
  const float* Wq    = (const float*)d_in[2];
  const float* Wk    = (const float*)d_in[3];
  const float* Wv    = (const float*)d_in[4];
  const float* a_src = (const float*)d_in[5];
  const float* a_dst = (const float*)d_in[6];
  const float* gamma = (const float*)d_in[7];
  const float* beta  = (const float*)d_in[8];
  float* out = (float*)d_out;

  char* ws = (char*)d_ws;
  _Float16* VT_g  = (_Float16*)ws;
  float*    s_src = (float*)(ws + 12582912);
  float*    s_dst = (float*)(ws + 13369344);
  unsigned char* maskb = (unsigned char*)(ws + 14155776);

  k1_v<<<832, 256, 0, stream>>>(x, Wv, Wq, Wk, a_src, a_dst, gso,
                                VT_g, s_src, s_dst, maskb);
  k2_attn<<<1536, 256, 0, stream>>>(VT_g, s_src, s_dst, maskb, gamma, beta, out);
}

// Round 11
// 130.780 us; speedup vs baseline: 1.3395x; 1.3395x over previous
//
#include <hip/hip_runtime.h>

#define CDIM 64
#define TDIM 24
#define NDIM 512
#define NBT  192   // B*T = 8*24

typedef float    float4v __attribute__((ext_vector_type(4)));
typedef _Float16 half8v  __attribute__((ext_vector_type(8)));
typedef _Float16 half4v  __attribute__((ext_vector_type(4)));
typedef _Float16 half2v  __attribute__((ext_vector_type(2)));

// ---------------------------------------------------------------------------
// Workspace layout (bytes):
//   VT_g   : _Float16 [NBT][64][512]   0          (12582912 B)
//   s_src  : float    [NBT][2][512]    12582912   (786432 B)   (exp2 domain)
//   s_dst  : float    [NBT][2][512]    13369344   (786432 B)   (exp2 domain)
//   maskb  : u8       [512][512]       14155776   (262144 B)   {0x00,0xFF}
// XCD note: both kernels use 1D grids with bt = bx % NBT, so all blocks
// sharing a bt land on XCD bt%8: VT[bt] is produced and consumed in the same
// XCD's L2 (verified R9: FETCH 52.8 -> 27.2 MB).
// ---------------------------------------------------------------------------

__device__ __forceinline__ float exp2_fast(float x) {
#if __has_builtin(__builtin_amdgcn_exp2f)
  return __builtin_amdgcn_exp2f(x);
#else
  return __expf(x * 0.69314718f);
#endif
}

__device__ __forceinline__ half2v pk2(float a, float b) {
  return __builtin_bit_cast(half2v, __builtin_amdgcn_cvt_pkrtz(a, b));
}

// ======== kernel 1: V = X @ Wv^T (f16 MFMA) + score cols + mask pack ========
// (unchanged from R9 — never regressed, stays below the fill floor)
struct SmemK1 {
  union {
    _Float16 xt[128][72];    // X tile [node][c], 144 B rows (16B aligned, b128-readable)
    _Float16 vtb[64][136];   // V^T bounce [c][node]
  } big;                     // 18432 B
  _Float16 wv[64][72];       // Wv [d][k]             9216 B
  _Float16 wext[16][72];     // rows 0..3 = log2e * (a_h^T W_h), rest 0   2304 B
};                            // 29952 B -> 4 blocks/CU

__launch_bounds__(256, 4)
__global__ void k1_v(const float* __restrict__ x,  const float* __restrict__ Wv,
                     const float* __restrict__ Wq, const float* __restrict__ Wk,
                     const float* __restrict__ a_src, const float* __restrict__ a_dst,
                     const int* __restrict__ gso,
                     _Float16* __restrict__ VT_g,
                     float* __restrict__ s_src_g, float* __restrict__ s_dst_g,
                     unsigned char* __restrict__ maskb) {
  const int t  = threadIdx.x;
  const int bx = blockIdx.x;

  if (bx >= 768) {   // ---- mask-pack blocks: 16 ints -> 16 mask bytes each ----
    int g = (bx - 768) * 256 + t;            // 0..16383
    const int4* gp = (const int4*)gso + (size_t)g * 4;
    unsigned w[4];
#pragma unroll
    for (int k = 0; k < 4; ++k) {
      int4 v = gp[k];
      w[k] = (v.x ? 0x000000FFu : 0u) | (v.y ? 0x0000FF00u : 0u) |
             (v.z ? 0x00FF0000u : 0u) | (v.w ? 0xFF000000u : 0u);
    }
    uint4 o; o.x = w[0]; o.y = w[1]; o.z = w[2]; o.w = w[3];
    ((uint4*)maskb)[g] = o;
    return;
  }

  __shared__ SmemK1 sm;
  const int bt = bx % NBT;       // XCD = bt % 8
  const int qn = bx / NBT;
  const int b  = bt / TDIM, tt = bt % TDIM;
  const int n0 = qn * 128;

  // stage Wv -> f16 LDS (float4 + pkrtz, half4 stores)
#pragma unroll
  for (int it = 0; it < 4; ++it) {
    int idx = it * 256 + t;           // 1024 float4 chunks
    int d = idx >> 4, k4 = (idx & 15) * 4;
    float4 v = ((const float4*)Wv)[idx];
    half2v p0 = pk2(v.x, v.y), p1 = pk2(v.z, v.w);
    half4v h4; h4[0] = p0[0]; h4[1] = p0[1]; h4[2] = p1[0]; h4[3] = p1[1];
    *(half4v*)&sm.wv[d][k4] = h4;
  }
  // wext: zero rows 4..15; rows 0..3 = log2e * (a_h^T W_h)  (exp2 domain)
  for (int z = t; z < 12 * 72; z += 256) ((_Float16*)sm.wext[4])[z] = (_Float16)0.f;
  {
    int r = t >> 6, c = t & 63;
    const float* av = (r & 2) ? a_dst : a_src;
    const float* W  = (r & 2) ? Wk : Wq;
    int off = (r & 1) * 32;
    float s = 0.f;
#pragma unroll
    for (int d = 0; d < 32; ++d)
      s += av[off + d] * W[(off + d) * 64 + c];
    sm.wext[r][c] = (_Float16)(s * 1.44269504f);
  }
  // stage X tile (channel pairs -> half2)
  for (int it = 0; it < 16; ++it) {
    int idx = it * 256 + t;
    int cp = idx >> 7, n = idx & 127;
    int c0 = cp * 2;
    const float* base = x + ((size_t)(b * CDIM + c0) * TDIM + tt) * NDIM + n0 + n;
    *(half2v*)&sm.big.xt[n][c0] = pk2(base[0], base[(size_t)TDIM * NDIM]);
  }
  __syncthreads();

  const int lane = t & 63, w = t >> 6;
  const int m = lane & 15, quad = lane >> 4;
  const int mbase = w * 32;   // 32 nodes per wave

  float4v acc[2][5];
#pragma unroll
  for (int mt = 0; mt < 2; ++mt)
#pragma unroll
    for (int nt = 0; nt < 5; ++nt)
#pragma unroll
      for (int r = 0; r < 4; ++r) acc[mt][nt][r] = 0.f;

#pragma unroll
  for (int ks = 0; ks < 2; ++ks) {
    half8v af[2], bf[5];
#pragma unroll
    for (int mt = 0; mt < 2; ++mt)
      af[mt] = *(const half8v*)&sm.big.xt[mbase + mt * 16 + m][ks * 32 + quad * 8];
#pragma unroll
    for (int nt = 0; nt < 4; ++nt)
      bf[nt] = *(const half8v*)&sm.wv[nt * 16 + m][ks * 32 + quad * 8];
    bf[4] = *(const half8v*)&sm.wext[m][ks * 32 + quad * 8];
#pragma unroll
    for (int mt = 0; mt < 2; ++mt)
#pragma unroll
      for (int nt = 0; nt < 5; ++nt)
        acc[mt][nt] = __builtin_amdgcn_mfma_f32_16x16x32_f16(af[mt], bf[nt], acc[mt][nt], 0, 0, 0);
  }

  // scatter score columns (col 0/1 = ssrc h0/h1, col 2/3 = sdst h0/h1)
  if (m < 4) {
    float* basep = (m < 2 ? s_src_g : s_dst_g) + (size_t)(bt * 2 + (m & 1)) * NDIM;
#pragma unroll
    for (int mt = 0; mt < 2; ++mt)
#pragma unroll
      for (int r = 0; r < 4; ++r)
        basep[n0 + mbase + mt * 16 + quad * 4 + r] = acc[mt][4][r];
  }
  __syncthreads();   // xt fully consumed before overlay

  // V^T bounce into LDS (pack node pairs)
#pragma unroll
  for (int mt = 0; mt < 2; ++mt)
#pragma unroll
    for (int nt = 0; nt < 4; ++nt)
#pragma unroll
      for (int r = 0; r < 4; r += 2) {
        int nl = mbase + mt * 16 + quad * 4 + r;
        int c  = nt * 16 + m;
        *(half2v*)&sm.big.vtb[c][nl] = pk2(acc[mt][nt][r], acc[mt][nt][r + 1]);
      }
  __syncthreads();

  // coalesced V^T -> global (64 rows x 64 dwords)
  const unsigned* vdw = (const unsigned*)sm.big.vtb;   // row stride 68 dwords
  unsigned* outdw = (unsigned*)VT_g;
  for (int it = 0; it < 16; ++it) {
    int idx = it * 256 + t;
    int c = idx >> 6, jd = idx & 63;
    outdw[(size_t)(bt * 64 + c) * 256 + qn * 64 + jd] = vdw[c * 68 + jd];
  }
}

// ======== kernel 2: masked softmax(P) @ V + LayerNorm + transpose ===========
// 1D grid, 768 blocks: bt = bx % NBT (XCD-aligned), ip = bx / NBT -> 128
// i-rows per block (2 i-tiles, V-fragments reused 2x). BARRIER-FREE main
// loop: each wave reads only its own head's 32 V-rows, so V-fragments and
// mask bytes load per-lane direct from (XCD-local) L2 with an explicit
// depth-3 rolling prefetch (mod-3 slots, fully unrolled -> no spill).
// F/P broadcast factors live in LDS (conflict-free reads).
struct SmemK2 {
  union {
    struct { _Float16 F[2][512]; _Float16 P[2][512]; } f;  // 4096 B (dead after loop)
    struct { float rsum[2][128]; float rsq[2][128];
             float mu[128]; float rs[128]; } l;            // 3072 B
  } v;
  float otile[128][66];                                    // 33792 B
};                                                          // 37888 B

__launch_bounds__(256, 2)
__global__ void k2_attn(const _Float16* __restrict__ VT_g,
                        const float* __restrict__ s_src_g, const float* __restrict__ s_dst_g,
                        const unsigned char* __restrict__ maskb,
                        const float* __restrict__ gamma, const float* __restrict__ beta,
                        float* __restrict__ out) {
  __shared__ SmemK2 sm;
  const int t    = threadIdx.x;
  const int bx   = blockIdx.x;
  const int bt   = bx % NBT;    // XCD = bt % 8
  const int ip   = bx / NBT;
  const int i0   = ip * 128;
  const int b    = bt / TDIM, tt = bt % TDIM;
  const int lane = t & 63, w = t >> 6;
  const int h = w >> 1, ihalf = w & 1;
  const int m = lane & 15, quad = lane >> 4;

  // per-lane global pointers
  const _Float16* vrow = VT_g + ((size_t)bt * 64 + h * 32 + m) * NDIM;   // b0 row; b1 at +16*NDIM
  const unsigned char* mrow[4];
  mrow[0] = maskb + (size_t)(i0 + ihalf * 32 + m) * NDIM;   // tile A, sub 0
  mrow[1] = mrow[0] + 16 * NDIM;                            // tile A, sub 1
  mrow[2] = mrow[0] + 64 * NDIM;                            // tile B, sub 0
  mrow[3] = mrow[0] + 80 * NDIM;                            // tile B, sub 1

  // ---- depth-3 rolling prefetch: issue iterations 0,1 now ----
  half8v pv0[3], pv1[3];
  uint2  pm[3][4];
#pragma unroll
  for (int k = 0; k < 2; ++k) {
    int jo = k * 32 + quad * 8;
    pv0[k] = *(const half8v*)(vrow + jo);
    pv1[k] = *(const half8v*)(vrow + 16 * NDIM + jo);
#pragma unroll
    for (int mt = 0; mt < 4; ++mt) pm[k][mt] = *(const uint2*)(mrow[mt] + jo);
  }

  // ---- F/P staging (overlaps prologue load latency) ----
  for (int it = 0; it < 4; ++it) {
    int idx = it * 256 + t;
    float d = s_dst_g[(size_t)bt * 2 * NDIM + idx];
    ((_Float16*)sm.v.f.F)[idx] = (_Float16)exp2_fast(d);
    ((_Float16*)sm.v.f.P)[idx] = (_Float16)exp2_fast(0.2f * d);
  }
  half8v E8[4], Q8[4];
#pragma unroll
  for (int mt = 0; mt < 4; ++mt) {
    int irow = i0 + (mt >> 1) * 64 + ihalf * 32 + (mt & 1) * 16 + m;
    float sv = s_src_g[(size_t)(bt * 2 + h) * NDIM + irow];
    _Float16 ev = (_Float16)exp2_fast(sv - 6.f);
    _Float16 qv = (_Float16)exp2_fast(0.2f * sv - 6.f);
#pragma unroll
    for (int jj = 0; jj < 8; ++jj) { E8[mt][jj] = ev; Q8[mt][jj] = qv; }
  }

  float4v acc[4][2], accs[4];
#pragma unroll
  for (int mt = 0; mt < 4; ++mt)
#pragma unroll
    for (int r = 0; r < 4; ++r) { acc[mt][0][r] = 0.f; acc[mt][1][r] = 0.f; accs[mt][r] = 0.f; }
  const half8v bones = {(_Float16)1.f, (_Float16)1.f, (_Float16)1.f, (_Float16)1.f,
                        (_Float16)1.f, (_Float16)1.f, (_Float16)1.f, (_Float16)1.f};

  __syncthreads();   // F/P visible; ONLY barrier before epilogue

  // ---- main loop: 16 x 32 j-columns, zero barriers ----
#pragma unroll
  for (int it = 0; it < 16; ++it) {
    const int s = it % 3;
    if (it < 14) {                       // prefetch iteration it+2 into slot (it+2)%3
      const int f = (it + 2) % 3;
      const int jo = (it + 2) * 32 + quad * 8;
      pv0[f] = *(const half8v*)(vrow + jo);
      pv1[f] = *(const half8v*)(vrow + 16 * NDIM + jo);
#pragma unroll
      for (int mt = 0; mt < 4; ++mt) pm[f][mt] = *(const uint2*)(mrow[mt] + jo);
    }
    const int jo = it * 32 + quad * 8;
    half8v F8 = *(const half8v*)&sm.v.f.F[h][jo];
    half8v P8 = *(const half8v*)&sm.v.f.P[h][jo];
#pragma unroll
    for (int mt = 0; mt < 4; ++mt) {
      half8v e8 = __builtin_elementwise_max(E8[mt] * F8, Q8[mt] * P8);  // pk_mul/pk_max
      uint4 eu = __builtin_bit_cast(uint4, e8);
      uint2 mv = pm[s][mt];
      eu.x &= __builtin_amdgcn_perm(0u, mv.x, 0x01010000u);
      eu.y &= __builtin_amdgcn_perm(0u, mv.x, 0x03030202u);
      eu.z &= __builtin_amdgcn_perm(0u, mv.y, 0x01010000u);
      eu.w &= __builtin_amdgcn_perm(0u, mv.y, 0x03030202u);
      half8v af = __builtin_bit_cast(half8v, eu);
      acc[mt][0] = __builtin_amdgcn_mfma_f32_16x16x32_f16(af, pv0[s], acc[mt][0], 0, 0, 0);
      acc[mt][1] = __builtin_amdgcn_mfma_f32_16x16x32_f16(af, pv1[s], acc[mt][1], 0, 0, 0);
      accs[mt]   = __builtin_amdgcn_mfma_f32_16x16x32_f16(af, bones,  accs[mt],   0, 0, 0);
    }
  }

  // ---- epilogue: normalize -> otile -> LayerNorm -> transposed store ----
#pragma unroll
  for (int mt = 0; mt < 4; ++mt)
#pragma unroll
    for (int r = 0; r < 4; ++r) {
      float sc = __builtin_amdgcn_rcpf(accs[mt][r]);
      int i_loc = (mt >> 1) * 64 + ihalf * 32 + (mt & 1) * 16 + quad * 4 + r;
#pragma unroll
      for (int nt = 0; nt < 2; ++nt)
        sm.otile[i_loc][h * 32 + nt * 16 + m] = acc[mt][nt][r] * sc;
    }
  __syncthreads();   // otile complete; F/P dead -> LN scratch overlay

  {
    int i = t & 127, cg = t >> 7;   // 2 col-groups x 32 channels
    float s1 = 0.f, s2 = 0.f;
#pragma unroll
    for (int cc = 0; cc < 32; ++cc) {
      float v = sm.otile[i][cg * 32 + cc];
      s1 += v; s2 += v * v;
    }
    sm.v.l.rsum[cg][i] = s1;
    sm.v.l.rsq[cg][i]  = s2;
  }
  __syncthreads();
  if (t < 128) {
    int i = t;
    float s1 = sm.v.l.rsum[0][i] + sm.v.l.rsum[1][i];
    float s2 = sm.v.l.rsq[0][i]  + sm.v.l.rsq[1][i];
    float mu  = s1 * (1.f / 64.f);
    float var = s2 * (1.f / 64.f) - mu * mu;
    sm.v.l.mu[i] = mu;
    sm.v.l.rs[i] = rsqrtf(var + 1e-5f);
  }
  __syncthreads();
  {
    int i = t & 127, cg = t >> 7;
    float mu = sm.v.l.mu[i], rs = sm.v.l.rs[i];
    int n = i0 + i;
#pragma unroll
    for (int cc = 0; cc < 32; ++cc) {
      int c = cg * 32 + cc;
      float v = (sm.otile[i][c] - mu) * rs * gamma[c] + beta[c];
      out[((size_t)(b * CDIM + c) * TDIM + tt) * NDIM + n] = v;
    }
  }
}

// ---------------------------------------------------------------------------
extern "C" void kernel_launch(void* const* d_in, const int* in_sizes, int n_in,
                              void* d_out, int out_size, void* d_ws, size_t ws_size,
                              hipStream_t stream) {
  const float* x     = (const float*)d_in[0];
  const int*   gso   = (const int*)d_in[1];
  const float* Wq    = (const float*)d_in[2];
  const float* Wk    = (const float*)d_in[3];
  const float* Wv    = (const float*)d_in[4];
  const float* a_src = (const float*)d_in[5];
  const float* a_dst = (const float*)d_in[6];
  const float* gamma = (const float*)d_in[7];
  const float* beta  = (const float*)d_in[8];
  float* out = (float*)d_out;

  char* ws = (char*)d_ws;
  _Float16* VT_g  = (_Float16*)ws;
  float*    s_src = (float*)(ws + 12582912);
  float*    s_dst = (float*)(ws + 13369344);
  unsigned char* maskb = (unsigned char*)(ws + 14155776);

  k1_v<<<832, 256, 0, stream>>>(x, Wv, Wq, Wk, a_src, a_dst, gso,
                                VT_g, s_src, s_dst, maskb);
  k2_attn<<<768, 256, 0, stream>>>(VT_g, s_src, s_dst, maskb, gamma, beta, out);
}